// Round 12
// baseline (168.275 us; speedup 1.0000x reference)
//
#include <hip/hip_runtime.h>

#define B_   32
#define T_   512
#define D_   512
#define F_   256
#define MEL  4096
#define EPS_ 1e-5f

#define PH1  24          // conv1 phases (64 k each, KT=1536)
#define PH2  12          // conv2 phases (KT=768)
#define PHT  36
#define GP   32          // gather sets (2 rows each) per wave -> 64 rows/wave

typedef __attribute__((ext_vector_type(8))) short bf16x8;
typedef __attribute__((ext_vector_type(4))) float f32x4;

#define GLL16(gp, lp) \
    __builtin_amdgcn_global_load_lds((const __attribute__((address_space(1))) void*)(gp), \
                                     (__attribute__((address_space(3))) void*)(lp), 16, 0, 0)
#define BARRIER() do { asm volatile("" ::: "memory"); __builtin_amdgcn_s_barrier(); \
                       asm volatile("" ::: "memory"); } while (0)
#define MEMPIN() asm volatile("" ::: "memory")

__device__ inline unsigned short f2bf(float f) {
    unsigned u = __float_as_uint(f);
    unsigned r = (u + 0x7fff + ((u >> 16) & 1)) >> 16;   // RNE
    return (unsigned short)r;
}

// ---------------------------------------------------------------------------
// prep: weight transpose/convert (blocks 0..2303) + per-batch cumsum & idx
// precompute (blocks 2304..2335). gidx[b][pos] = source row, or -1 (masked).
// ---------------------------------------------------------------------------
#define PREP_WBLOCKS 2304   // (3*D_*F_ + 3*F_*F_) / 256

__global__ __launch_bounds__(256)
void prep_kernel(const float* __restrict__ w1, const float* __restrict__ w2,
                 const int* __restrict__ tgt,
                 unsigned short* __restrict__ w1T, unsigned short* __restrict__ w2T,
                 int* __restrict__ gidx)
{
    __shared__ int lcum[T_];
    __shared__ int wsum[4];

    int bid = blockIdx.x;
    int tid = threadIdx.x;
    if (bid < PREP_WBLOCKS) {
        int idx = bid * 256 + tid;
        if (idx < 3 * D_ * F_) {
            int kk = idx / F_, f = idx % F_;
            w1T[(size_t)f * (3 * D_) + kk] = f2bf(w1[idx]);
        } else {
            int j = idx - 3 * D_ * F_;
            int kk = j / F_, f = j % F_;
            w2T[(size_t)f * (3 * F_) + kk] = f2bf(w2[j]);
        }
        return;
    }

    int b = bid - PREP_WBLOCKS;
    int t0 = tid * 2;
    int a0 = tgt[b * T_ + t0], a1 = tgt[b * T_ + t0 + 1];
    int lane = tid & 63, w = tid >> 6;
    int v = a0 + a1;
#pragma unroll
    for (int o = 1; o < 64; o <<= 1) { int u = __shfl_up(v, o); if (lane >= o) v += u; }
    if (lane == 63) wsum[w] = v;
    __syncthreads();
    int base = 0;
#pragma unroll
    for (int i = 0; i < 4; ++i) if (i < w) base += wsum[i];
    int incl = base + v;
    lcum[t0]     = incl - a1;
    lcum[t0 + 1] = incl;
    __syncthreads();

    int total = lcum[T_ - 1];
#pragma unroll
    for (int k = 0; k < MEL / 256; ++k) {
        int pos = tid + k * 256;
        int lo = 0, hi = T_;
        while (lo < hi) { int mid = (lo + hi) >> 1; if (lcum[mid] <= pos) lo = mid + 1; else hi = mid; }
        gidx[b * MEL + pos] = (pos < total) ? min(lo, T_ - 1) : -1;
    }
}

// ---------------------------------------------------------------------------
// Fully-fused: conv1(+LN+ReLU, h1 kept in LDS incl. 2 redundant halo rows) ->
// conv2(+LN+ReLU) -> dur_pred, with the length-regulator gather riding one
// continuous 36-phase counted-vmcnt pipeline. MT=64 output rows/block,
// 512 thr = 8 waves (2 rowgroups x 4 fgroups).
// conv1 computes 66 h1 rows (t0-1..t0+64): rg0 carries an extra m-frag
// (local rows 64..79; only 64,65 kept). A-tile 68 staged rows (t0-2..t0+65),
// padded to 84 rows so garbage m2-frag reads stay in-bounds.
// h2 is never stored: dur_pred folds into epilogue2.
// Body: [G_{p+2}][S_{p-1}][L_{p+2}]; set q loads at body q-2, stores at q+1.
// Ledger: prologue [gidx|G0|G1|L0|L1]; p0:12, p1:16,
// p>=2: 4*(1+[0<=p-3<GP]+[2<=p<GP]+[0<=p-2<GP]+[2<=p+1<GP]).
// ---------------------------------------------------------------------------
__global__ __launch_bounds__(512)
void fused_kernel(const float* __restrict__ x,
                  const unsigned short* __restrict__ w1T, const unsigned short* __restrict__ w2T,
                  const float* __restrict__ b1, const float* __restrict__ g1, const float* __restrict__ be1,
                  const float* __restrict__ b2, const float* __restrict__ g2, const float* __restrict__ be2,
                  const float* __restrict__ wl, const float* __restrict__ bl,
                  const int* __restrict__ gidx,
                  float* __restrict__ out, float* __restrict__ dur)
{
    __shared__ __align__(16) char xsA[84 * 512 * 2];          // A tile (68 rows used) -> h1 tile
    __shared__ __align__(16) unsigned short xsB[2 * 16384];   // 2 x 32 KB B buffers
    __shared__ float red[80][8];
    __shared__ float redD[64][4];

    const int b  = blockIdx.x >> 3;
    const int t0 = (blockIdx.x & 7) * 64;
    const int l  = threadIdx.x & 63;
    const int wv = threadIdx.x >> 6;
    const int fg = wv & 3;
    const int rg = wv >> 2;

    // ---- stage A rows t0-2 .. t0+65 (68 rows) as bf16, swizzled ----
    for (int c = threadIdx.x; c < 68 * 64; c += 512) {
        int j  = c >> 6;
        int d8 = (c & 63) * 8;
        int t  = t0 - 2 + j;
        uint4 pk = make_uint4(0u, 0u, 0u, 0u);
        if (t >= 0 && t < T_) {
            const float4* src = reinterpret_cast<const float4*>(&x[((size_t)b * T_ + t) * D_ + d8]);
            float4 a0 = src[0], a1 = src[1];
            pk.x = (unsigned)f2bf(a0.x) | ((unsigned)f2bf(a0.y) << 16);
            pk.y = (unsigned)f2bf(a0.z) | ((unsigned)f2bf(a0.w) << 16);
            pk.z = (unsigned)f2bf(a1.x) | ((unsigned)f2bf(a1.y) << 16);
            pk.w = (unsigned)f2bf(a1.z) | ((unsigned)f2bf(a1.w) << 16);
        }
        int byte = ((j * 512 + d8) * 2) ^ ((j & 7) << 4);
        *reinterpret_cast<uint4*>(&xsA[byte]) = pk;
    }

    // ---- epilogue scalars (before ledger baseline) ----
    float bv1[4], gv1[4], bev1[4], bv2[4], gv2[4], bev2[4], wlv[4];
#pragma unroll
    for (int n = 0; n < 4; ++n) {
        int f = fg * 64 + n * 16 + (l & 15);
        bv1[n] = b1[f]; gv1[n] = g1[f]; bev1[n] = be1[f];
        bv2[n] = b2[f]; gv2[n] = g2[f]; bev2[n] = be2[f];
        wlv[n] = wl[f];
    }
    float blv = bl[0];

    asm volatile("s_waitcnt vmcnt(0)" ::: "memory");   // ledger baseline
    __syncthreads();

    // ---- gather: 64 consecutive rows per wave ----
    const int rbase = (blockIdx.x * 8 + wv) * 64;
    int gidxv = gidx[rbase + l];
    MEMPIN();

    // ---- B staging: [256 f][8 kg][8 k], slot XOR kg^(f&7); gll dest linear ----
    const int sbase = wv * 4;
    auto stageB = [&](int ph, int buf) {
        unsigned short* lb = &xsB[buf * 16384];
        const unsigned short* wsrc;
        int KTc, phc;
        if (ph < PH1) { wsrc = w1T; KTc = 1536; phc = ph; }
        else          { wsrc = w2T; KTc = 768;  phc = (ph - PH1 < PH2) ? ph - PH1 : PH2 - 1; }
#pragma unroll
        for (int i = 0; i < 4; ++i) {
            int s = sbase + i;
            int c = s * 64 + l;
            int f = c >> 3;
            int kg = (c & 7) ^ (f & 7);
            const unsigned short* src = wsrc + (size_t)f * KTc + phc * 64 + kg * 8;
            GLL16(src, lb + s * 512);
        }
    };
    auto loadBfrag = [&](bf16x8* dst, int buf, int kk2) {
#pragma unroll
        for (int n = 0; n < 4; ++n) {
            int f  = fg * 64 + n * 16 + (l & 15);
            int kg = kk2 * 4 + (l >> 4);
            dst[n] = *reinterpret_cast<const bf16x8*>(&xsB[buf * 16384 + f * 64 + ((kg ^ (f & 7)) * 8)]);
        }
    };
    const int k_lane = (l >> 4) * 8;

    // gather set load/store: 2 rows/set, 2 dwordx4 per lane per row
    float4 ga[3][2][2];
    auto loadSet = [&](int slot, int s) {
#pragma unroll
        for (int i = 0; i < 2; ++i) {
            int li = 2 * s + i;
            int ix = __shfl(gidxv, li);
            int r  = rbase + li;
            const float* src = x + ((size_t)(r >> 12) * T_ + max(ix, 0)) * D_ + l * 4;
            ga[slot][i][0] = *reinterpret_cast<const float4*>(src);
            ga[slot][i][1] = *reinterpret_cast<const float4*>(src + 256);
        }
    };
    auto storeSet = [&](int slot, int s) {
#pragma unroll
        for (int i = 0; i < 2; ++i) {
            int li = 2 * s + i;
            int ix = __shfl(gidxv, li);
            int r  = rbase + li;
            float4 a = ga[slot][i][0], c = ga[slot][i][1];
            if (ix < 0) { a = make_float4(0.f,0.f,0.f,0.f); c = make_float4(0.f,0.f,0.f,0.f); }
            float* d = out + (size_t)r * D_ + l * 4;
            *reinterpret_cast<float4*>(d)       = a;
            *reinterpret_cast<float4*>(d + 256) = c;
        }
    };

    f32x4 acc1[3][4], acc2[2][4];
#pragma unroll
    for (int n = 0; n < 4; ++n) {
#pragma unroll
        for (int m = 0; m < 3; ++m) acc1[m][n] = (f32x4){0.f, 0.f, 0.f, 0.f};
#pragma unroll
        for (int m = 0; m < 2; ++m) acc2[m][n] = (f32x4){0.f, 0.f, 0.f, 0.f};
    }

    // ---- prologue: [G0][G1][L0][L1] ----
    stageB(0, 0);  MEMPIN();
    stageB(1, 1);  MEMPIN();
    loadSet(0, 0); MEMPIN();
    loadSet(1, 1); MEMPIN();

    // ---- 36-phase pipeline ----
#pragma unroll
    for (int p = 0; p < PHT; ++p) {
        const int nw = (p == 0) ? 12 : (p == 1) ? 16
                     : 4 * (1 + ((p >= 3 && p - 3 < GP) ? 1 : 0)
                              + ((p >= 2 && p < GP) ? 1 : 0)
                              + ((p - 2 < GP) ? 1 : 0)
                              + ((p + 1 >= 2 && p + 1 < GP) ? 1 : 0));
        if      (nw == 20) asm volatile("s_waitcnt vmcnt(20)" ::: "memory");
        else if (nw == 16) asm volatile("s_waitcnt vmcnt(16)" ::: "memory");
        else if (nw == 12) asm volatile("s_waitcnt vmcnt(12)" ::: "memory");
        else if (nw == 8)  asm volatile("s_waitcnt vmcnt(8)"  ::: "memory");
        else               asm volatile("s_waitcnt vmcnt(4)"  ::: "memory");
        BARRIER();
        const int buf = p & 1;
#pragma unroll
        for (int kk2 = 0; kk2 < 2; ++kk2) {
            bf16x8 Bv[4];
            loadBfrag(Bv, buf, kk2);
            if (p < PH1) {
                int kk = p * 64 + kk2 * 32;
                int kp = kk / 512;
                int dbase = (kk % 512) + k_lane;
#pragma unroll
                for (int m = 0; m < 2; ++m) {
                    int j = rg * 32 + m * 16 + (l & 15) + kp;
                    bf16x8 Av = *reinterpret_cast<const bf16x8*>(
                        &xsA[((j * 512 + dbase) * 2) ^ ((j & 7) << 4)]);
#pragma unroll
                    for (int n = 0; n < 4; ++n)
                        acc1[m][n] = __builtin_amdgcn_mfma_f32_16x16x32_bf16(Av, Bv[n], acc1[m][n], 0, 0, 0);
                }
                if (rg == 0) {                       // halo m-frag: local rows 64..79
                    int j = 64 + (l & 15) + kp;
                    bf16x8 Av = *reinterpret_cast<const bf16x8*>(
                        &xsA[((j * 512 + dbase) * 2) ^ ((j & 7) << 4)]);
#pragma unroll
                    for (int n = 0; n < 4; ++n)
                        acc1[2][n] = __builtin_amdgcn_mfma_f32_16x16x32_bf16(Av, Bv[n], acc1[2][n], 0, 0, 0);
                }
            } else {
                int kk = (p - PH1) * 64 + kk2 * 32;
                int kp = kk / 256;
                int dbase = (kk % 256) + k_lane;
#pragma unroll
                for (int m = 0; m < 2; ++m) {
                    int j = rg * 32 + m * 16 + (l & 15) + kp;
                    bf16x8 Av = *reinterpret_cast<const bf16x8*>(
                        &xsA[((j * 256 + dbase) * 2) ^ ((j & 7) << 4)]);
#pragma unroll
                    for (int n = 0; n < 4; ++n)
                        acc2[m][n] = __builtin_amdgcn_mfma_f32_16x16x32_bf16(Av, Bv[n], acc2[m][n], 0, 0, 0);
                }
            }
        }
        BARRIER();
        // body: [G_{p+2}][S_{p-1}][L_{p+2}]
        stageB(p + 2, buf);                                   MEMPIN();
        if (p >= 1 && p - 1 < GP) { storeSet((p - 1) % 3, p - 1); MEMPIN(); }
        if (p + 2 < GP)           { loadSet((p + 2) % 3, p + 2); MEMPIN(); }

        if (p == PH1 - 1) {
            // ---- epilogue1: bias+LN+ReLU -> h1 tile in xsA (66 rows) ----
            __syncthreads();                          // A reads done; red free
#pragma unroll
            for (int m = 0; m < 3; ++m) {
                if (m < 2 || rg == 0) {
#pragma unroll
                    for (int q = 0; q < 4; ++q) {
                        float s = 0.f, s2 = 0.f;
#pragma unroll
                        for (int n = 0; n < 4; ++n) {
                            float v2 = acc1[m][n][q] + bv1[n];
                            acc1[m][n][q] = v2;
                            s += v2; s2 += v2 * v2;
                        }
#pragma unroll
                        for (int o = 1; o < 16; o <<= 1) { s += __shfl_xor(s, o); s2 += __shfl_xor(s2, o); }
                        int row = (m < 2 ? rg * 32 + m * 16 : 64) + (l >> 4) * 4 + q;
                        if ((l & 15) == 0) { red[row][fg * 2] = s; red[row][fg * 2 + 1] = s2; }
                    }
                }
            }
            __syncthreads();
#pragma unroll
            for (int m = 0; m < 3; ++m) {
                if (m < 2 || rg == 0) {
#pragma unroll
                    for (int q = 0; q < 4; ++q) {
                        int row = (m < 2 ? rg * 32 + m * 16 : 64) + (l >> 4) * 4 + q;
                        if (row < 66) {
                            float s  = red[row][0] + red[row][2] + red[row][4] + red[row][6];
                            float s2 = red[row][1] + red[row][3] + red[row][5] + red[row][7];
                            float mu  = s * (1.f / F_);
                            float var = s2 * (1.f / F_) - mu * mu;
                            float rs  = rsqrtf(var + EPS_);
                            int t = t0 - 1 + row;
                            bool valid = (t >= 0 && t < T_);
#pragma unroll
                            for (int n = 0; n < 4; ++n) {
                                float y = (acc1[m][n][q] - mu) * rs * gv1[n] + bev1[n];
                                y = fmaxf(y, 0.f);
                                int col = fg * 64 + n * 16 + (l & 15);
                                int byte = ((row * 256 + col) * 2) ^ ((row & 7) << 4);
                                *reinterpret_cast<unsigned short*>(&xsA[byte]) = valid ? f2bf(y) : 0;
                            }
                        }
                    }
                }
            }
            __syncthreads();                          // h1 ready for conv2 reads
        }
    }

    // ---- epilogue2: bias+LN+ReLU -> dur only (h2 never stored) ----
#pragma unroll
    for (int m = 0; m < 2; ++m)
#pragma unroll
        for (int q = 0; q < 4; ++q) {
            float s = 0.f, s2 = 0.f;
#pragma unroll
            for (int n = 0; n < 4; ++n) {
                float v2 = acc2[m][n][q] + bv2[n];
                acc2[m][n][q] = v2;
                s += v2; s2 += v2 * v2;
            }
#pragma unroll
            for (int o = 1; o < 16; o <<= 1) { s += __shfl_xor(s, o); s2 += __shfl_xor(s2, o); }
            int row = rg * 32 + m * 16 + (l >> 4) * 4 + q;
            if ((l & 15) == 0) { red[row][fg * 2] = s; red[row][fg * 2 + 1] = s2; }
        }
    __syncthreads();

#pragma unroll
    for (int m = 0; m < 2; ++m)
#pragma unroll
        for (int q = 0; q < 4; ++q) {
            int row = rg * 32 + m * 16 + (l >> 4) * 4 + q;
            float s  = red[row][0] + red[row][2] + red[row][4] + red[row][6];
            float s2 = red[row][1] + red[row][3] + red[row][5] + red[row][7];
            float mu  = s * (1.f / F_);
            float var = s2 * (1.f / F_) - mu * mu;
            float rs  = rsqrtf(var + EPS_);
            float part = 0.f;
#pragma unroll
            for (int n = 0; n < 4; ++n) {
                float y = (acc2[m][n][q] - mu) * rs * gv2[n] + bev2[n];
                part = fmaf(fmaxf(y, 0.f), wlv[n], part);
            }
#pragma unroll
            for (int o = 1; o < 16; o <<= 1) part += __shfl_xor(part, o);
            if ((l & 15) == 0) redD[row][fg] = part;
        }
    __syncthreads();

    if (threadIdx.x < 64) {
        float s = redD[threadIdx.x][0] + redD[threadIdx.x][1]
                + redD[threadIdx.x][2] + redD[threadIdx.x][3] + blv;
        dur[(size_t)b * T_ + t0 + threadIdx.x] = fmaxf(s, 0.f);
    }
}

extern "C" void kernel_launch(void* const* d_in, const int* in_sizes, int n_in,
                              void* d_out, int out_size, void* d_ws, size_t ws_size,
                              hipStream_t stream)
{
    const float* x      = (const float*)d_in[0];
    const int*   target = (const int*)d_in[1];
    const float* w1  = (const float*)d_in[3];
    const float* b1  = (const float*)d_in[4];
    const float* g1  = (const float*)d_in[5];
    const float* be1 = (const float*)d_in[6];
    const float* w2  = (const float*)d_in[7];
    const float* b2  = (const float*)d_in[8];
    const float* g2  = (const float*)d_in[9];
    const float* be2 = (const float*)d_in[10];
    const float* wl  = (const float*)d_in[11];
    const float* bl  = (const float*)d_in[12];

    float* out = (float*)d_out;                        // (B, MEL, D)
    float* dur = out + (size_t)B_ * MEL * D_;          // (B, T)

    char* ws = (char*)d_ws;
    unsigned short* w1T = (unsigned short*)ws;         ws += (size_t)F_ * (3 * D_) * 2;
    unsigned short* w2T = (unsigned short*)ws;         ws += (size_t)F_ * (3 * F_) * 2;
    int*            gidx = (int*)ws;                   // B_*MEL ints

    prep_kernel<<<PREP_WBLOCKS + B_, 256, 0, stream>>>(w1, w2, target, w1T, w2T, gidx);

    fused_kernel<<<B_ * (T_ / 64), 512, 0, stream>>>(
        x, w1T, w2T, b1, g1, be1, b2, g2, be2, wl, bl, gidx, out, dur);
}

// Round 13
// 102.043 us; speedup vs baseline: 1.6491x; 1.6491x over previous
//
#include <hip/hip_runtime.h>
#include <type_traits>

#define B_   32
#define T_   512
#define D_   512
#define F_   256
#define MEL  4096
#define EPS_ 1e-5f

typedef __attribute__((ext_vector_type(8))) short bf16x8;
typedef __attribute__((ext_vector_type(4))) float f32x4;

#define GLL16(gp, lp) \
    __builtin_amdgcn_global_load_lds((const __attribute__((address_space(1))) void*)(gp), \
                                     (__attribute__((address_space(3))) void*)(lp), 16, 0, 0)
#define BARRIER() do { asm volatile("" ::: "memory"); __builtin_amdgcn_s_barrier(); \
                       asm volatile("" ::: "memory"); } while (0)
#define MEMPIN() asm volatile("" ::: "memory")

__device__ inline unsigned short f2bf(float f) {
    unsigned u = __float_as_uint(f);
    unsigned r = (u + 0x7fff + ((u >> 16) & 1)) >> 16;   // RNE
    return (unsigned short)r;
}

// ---------------------------------------------------------------------------
// prep: weight transpose/convert (blocks 0..2303) + per-batch cumsum & idx
// precompute (blocks 2304..2335). gidx[b][pos] = source row, or -1 (masked).
// ---------------------------------------------------------------------------
#define PREP_WBLOCKS 2304   // (3*D_*F_ + 3*F_*F_) / 256

__global__ __launch_bounds__(256)
void prep_kernel(const float* __restrict__ w1, const float* __restrict__ w2,
                 const int* __restrict__ tgt,
                 unsigned short* __restrict__ w1T, unsigned short* __restrict__ w2T,
                 int* __restrict__ gidx)
{
    __shared__ int lcum[T_];
    __shared__ int wsum[4];

    int bid = blockIdx.x;
    int tid = threadIdx.x;
    if (bid < PREP_WBLOCKS) {
        int idx = bid * 256 + tid;
        if (idx < 3 * D_ * F_) {
            int kk = idx / F_, f = idx % F_;
            w1T[(size_t)f * (3 * D_) + kk] = f2bf(w1[idx]);
        } else {
            int j = idx - 3 * D_ * F_;
            int kk = j / F_, f = j % F_;
            w2T[(size_t)f * (3 * F_) + kk] = f2bf(w2[j]);
        }
        return;
    }

    int b = bid - PREP_WBLOCKS;
    int t0 = tid * 2;
    int a0 = tgt[b * T_ + t0], a1 = tgt[b * T_ + t0 + 1];
    int lane = tid & 63, w = tid >> 6;
    int v = a0 + a1;
#pragma unroll
    for (int o = 1; o < 64; o <<= 1) { int u = __shfl_up(v, o); if (lane >= o) v += u; }
    if (lane == 63) wsum[w] = v;
    __syncthreads();
    int base = 0;
#pragma unroll
    for (int i = 0; i < 4; ++i) if (i < w) base += wsum[i];
    int incl = base + v;
    lcum[t0]     = incl - a1;
    lcum[t0 + 1] = incl;
    __syncthreads();

    int total = lcum[T_ - 1];
#pragma unroll
    for (int k = 0; k < MEL / 256; ++k) {
        int pos = tid + k * 256;
        int lo = 0, hi = T_;
        while (lo < hi) { int mid = (lo + hi) >> 1; if (lcum[mid] <= pos) lo = mid + 1; else hi = mid; }
        gidx[b * MEL + pos] = (pos < total) ? min(lo, T_ - 1) : -1;
    }
}

// ---------------------------------------------------------------------------
// Fused conv1d(K=3,SAME)+bias+LN+ReLU via bf16 MFMA, gather rows riding the
// same counted-vmcnt pipeline (R7/R10 structure, MT=64, 8 waves = 2rg x 4fg).
// BATCH-LOCAL gather: block (b,seg), wave wv owns mel chunk
// b*MEL + (seg*8+wv)*64, rows [GOFF, GOFF+2*GP) — sources lie in a ~40 KB
// band of x[b], L2-resident from A-staging (kills cross-XCD x re-fetch).
// Body [G_{p+2}][S_{p-1}][L_{p+2}]; ledger: prologue [gidx|G0|G1|L0|L1];
// p0:12, p1:16, p>=2: 4*(1+[0<=p-3<GP]+[p<GP]+[0<=p-2<GP]+[p+1<GP]).
// STORE_OUT=false (conv2) skips the dead h2 store (dur fused in epilogue).
// ---------------------------------------------------------------------------
template<int IN_D, typename InT, bool FUSE_DUR, bool STORE_OUT, int GP, int GOFF>
__global__ __launch_bounds__(512)
void conv_mfma_kernel(const InT* __restrict__ x, const unsigned short* __restrict__ wT,
                      const float* __restrict__ bias, const float* __restrict__ gamma,
                      const float* __restrict__ beta, unsigned short* __restrict__ out,
                      const float* __restrict__ wl, const float* __restrict__ bl,
                      float* __restrict__ dur,
                      const float* __restrict__ xf, const int* __restrict__ gidx,
                      float* __restrict__ gout)
{
    constexpr int MT = 64;
    constexpr int KT = 3 * IN_D;
    constexpr int PHASES = KT / 64;                  // 24 (conv1) / 12 (conv2)
    static_assert(GP < PHASES, "all gather stores must land in-loop");

    __shared__ __align__(16) char xs_raw[(MT + 2) * IN_D * 2];
    __shared__ __align__(16) unsigned short xsB[2 * 16384];   // 2 x 32 KB B buffers
    __shared__ float red[MT][8];
    __shared__ float redD[MT][4];

    const int blocksPerBatch = T_ / MT;              // 8
    const int b  = blockIdx.x / blocksPerBatch;
    const int seg = blockIdx.x % blocksPerBatch;
    const int t0 = seg * MT;
    const int l  = threadIdx.x & 63;
    const int wv = threadIdx.x >> 6;                 // 0..7
    const int fg = wv & 3;
    const int rg = wv >> 2;

    // ---- stage A rows t0-1 .. t0+MT into LDS as bf16, swizzled ----
    constexpr int CH = (MT + 2) * IN_D / 8;
    for (int c = threadIdx.x; c < CH; c += 512) {
        int j  = c / (IN_D / 8);
        int d8 = (c % (IN_D / 8)) * 8;
        int t  = t0 - 1 + j;
        uint4 pk = make_uint4(0u, 0u, 0u, 0u);
        if (t >= 0 && t < T_) {
            if constexpr (std::is_same_v<InT, float>) {
                const float4* src = reinterpret_cast<const float4*>(&x[((size_t)b * T_ + t) * IN_D + d8]);
                float4 a0 = src[0], a1 = src[1];
                pk.x = (unsigned)f2bf(a0.x) | ((unsigned)f2bf(a0.y) << 16);
                pk.y = (unsigned)f2bf(a0.z) | ((unsigned)f2bf(a0.w) << 16);
                pk.z = (unsigned)f2bf(a1.x) | ((unsigned)f2bf(a1.y) << 16);
                pk.w = (unsigned)f2bf(a1.z) | ((unsigned)f2bf(a1.w) << 16);
            } else {
                pk = *reinterpret_cast<const uint4*>(&x[((size_t)b * T_ + t) * IN_D + d8]);
            }
        }
        int byte = ((j * IN_D + d8) * 2) ^ ((j & 7) << 4);
        *reinterpret_cast<uint4*>(&xs_raw[byte]) = pk;
    }

    float bv[4], gv[4], bev[4], wlv[4];
#pragma unroll
    for (int n = 0; n < 4; ++n) {
        int f = fg * 64 + n * 16 + (l & 15);
        bv[n] = bias[f]; gv[n] = gamma[f]; bev[n] = beta[f];
        if constexpr (FUSE_DUR) wlv[n] = wl[f];
    }
    float blv = 0.f;
    if constexpr (FUSE_DUR) blv = bl[0];

    asm volatile("s_waitcnt vmcnt(0)" ::: "memory");   // ledger baseline
    __syncthreads();

    // ---- gather: batch-local chunk, rows [GOFF, GOFF+2*GP) of 64 ----
    constexpr int GROWS = 2 * GP;
    const int rbase = b * MEL + (seg * 8 + wv) * 64 + GOFF;
    int gidxv = gidx[rbase + min(l, GROWS - 1)];       // 1 vmem load
    MEMPIN();

    // ---- B staging: [256 f][8 kg][8 k], slot XOR kg^(f&7); gll dest linear ----
    const int sbase = wv * 4;
    auto stageB = [&](int ph, int buf) {
        int p = ph < PHASES ? ph : PHASES - 1;
        unsigned short* lb = &xsB[buf * 16384];
#pragma unroll
        for (int i = 0; i < 4; ++i) {
            int s = sbase + i;
            int c = s * 64 + l;
            int f = c >> 3;
            int kg = (c & 7) ^ (f & 7);
            const unsigned short* src = wT + (size_t)f * KT + p * 64 + kg * 8;
            GLL16(src, lb + s * 512);
        }
    };
    auto loadBfrag = [&](bf16x8* dst, int buf, int kk2) {
#pragma unroll
        for (int n = 0; n < 4; ++n) {
            int f  = fg * 64 + n * 16 + (l & 15);
            int kg = kk2 * 4 + (l >> 4);
            dst[n] = *reinterpret_cast<const bf16x8*>(&xsB[buf * 16384 + f * 64 + ((kg ^ (f & 7)) * 8)]);
        }
    };
    const int k_lane = (l >> 4) * 8;
    auto loadA = [&](bf16x8* dst, int kk) {
        int kp = kk / IN_D;
        int dbase = (kk % IN_D) + k_lane;
#pragma unroll
        for (int m = 0; m < 2; ++m) {
            int j = rg * 32 + m * 16 + (l & 15) + kp;
            int byte = ((j * IN_D + dbase) * 2) ^ ((j & 7) << 4);
            dst[m] = *reinterpret_cast<const bf16x8*>(&xs_raw[byte]);
        }
    };

    // gather set load/store: 2 rows/set, 2 dwordx4 per lane per row.
    // ALWAYS load (clamped idx) so the per-wave vmcnt ledger is exact.
    float4 ga[3][2][2];
    auto loadSet = [&](int slot, int s) {
#pragma unroll
        for (int i = 0; i < 2; ++i) {
            int li = 2 * s + i;
            int ix = __shfl(gidxv, li);
            const float* src = xf + ((size_t)b * T_ + max(ix, 0)) * D_ + l * 4;
            ga[slot][i][0] = *reinterpret_cast<const float4*>(src);
            ga[slot][i][1] = *reinterpret_cast<const float4*>(src + 256);
        }
    };
    auto storeSet = [&](int slot, int s) {
#pragma unroll
        for (int i = 0; i < 2; ++i) {
            int li = 2 * s + i;
            int ix = __shfl(gidxv, li);
            int r  = rbase + li;
            float4 a = ga[slot][i][0], c = ga[slot][i][1];
            if (ix < 0) { a = make_float4(0.f,0.f,0.f,0.f); c = make_float4(0.f,0.f,0.f,0.f); }
            float* d = gout + (size_t)r * D_ + l * 4;
            *reinterpret_cast<float4*>(d)       = a;
            *reinterpret_cast<float4*>(d + 256) = c;
        }
    };

    f32x4 acc[2][4];
#pragma unroll
    for (int m = 0; m < 2; ++m)
#pragma unroll
        for (int n = 0; n < 4; ++n) acc[m][n] = (f32x4){0.f, 0.f, 0.f, 0.f};

    // ---- prologue: [gidx][G0][G1][L0][L1], order pinned; set 2 loads in body 0 ----
    stageB(0, 0);  MEMPIN();
    stageB(1, 1);  MEMPIN();
    loadSet(0, 0); MEMPIN();
    loadSet(1, 1); MEMPIN();

    // ---- phase loop ----
#pragma unroll
    for (int p = 0; p < PHASES; ++p) {
        const int nw = (p == 0) ? 12 : (p == 1) ? 16
                     : 4 * (1 + ((p >= 3 && p - 3 < GP) ? 1 : 0) + ((p < GP) ? 1 : 0) +
                                ((p - 2 < GP) ? 1 : 0) + ((p + 1 < GP) ? 1 : 0));
        if      (nw == 20) asm volatile("s_waitcnt vmcnt(20)" ::: "memory");
        else if (nw == 16) asm volatile("s_waitcnt vmcnt(16)" ::: "memory");
        else if (nw == 12) asm volatile("s_waitcnt vmcnt(12)" ::: "memory");
        else if (nw == 8)  asm volatile("s_waitcnt vmcnt(8)"  ::: "memory");
        else               asm volatile("s_waitcnt vmcnt(4)"  ::: "memory");
        BARRIER();
        int buf = p & 1;
#pragma unroll
        for (int kk2 = 0; kk2 < 2; ++kk2) {
            int kk = p * 64 + kk2 * 32;
            bf16x8 Bv[4], Av[2];
            loadBfrag(Bv, buf, kk2);
            loadA(Av, kk);
#pragma unroll
            for (int m = 0; m < 2; ++m)
#pragma unroll
                for (int n = 0; n < 4; ++n)
                    acc[m][n] = __builtin_amdgcn_mfma_f32_16x16x32_bf16(Av[m], Bv[n], acc[m][n], 0, 0, 0);
        }
        BARRIER();
        // body: [G_{p+2}][S_{p-1}][L_{p+2}]
        stageB(p + 2, buf);                                  MEMPIN();
        if (p >= 1 && p - 1 < GP) { storeSet((p - 1) % 3, p - 1); MEMPIN(); }
        if (p + 2 < GP)           { loadSet((p + 2) % 3, p + 2); MEMPIN(); }
    }

    // ---- epilogue: bias, LN stats, LN+ReLU store, optional fused dur ----
#pragma unroll
    for (int m = 0; m < 2; ++m)
#pragma unroll
        for (int q = 0; q < 4; ++q) {
            float s = 0.f, s2 = 0.f;
#pragma unroll
            for (int n = 0; n < 4; ++n) {
                float v2 = acc[m][n][q] + bv[n];
                acc[m][n][q] = v2;
                s += v2; s2 += v2 * v2;
            }
#pragma unroll
            for (int o = 1; o < 16; o <<= 1) { s += __shfl_xor(s, o); s2 += __shfl_xor(s2, o); }
            int row = rg * 32 + m * 16 + (l >> 4) * 4 + q;   // C/D: col=l&15, row=(l>>4)*4+q
            if ((l & 15) == 0) { red[row][fg * 2] = s; red[row][fg * 2 + 1] = s2; }
        }
    __syncthreads();

#pragma unroll
    for (int m = 0; m < 2; ++m)
#pragma unroll
        for (int q = 0; q < 4; ++q) {
            int row = rg * 32 + m * 16 + (l >> 4) * 4 + q;
            float s  = red[row][0] + red[row][2] + red[row][4] + red[row][6];
            float s2 = red[row][1] + red[row][3] + red[row][5] + red[row][7];
            float mu  = s * (1.f / F_);
            float var = s2 * (1.f / F_) - mu * mu;
            float rs  = rsqrtf(var + EPS_);
            size_t rb2 = ((size_t)(b * T_ + t0 + row)) * F_;
            float part = 0.f;
#pragma unroll
            for (int n = 0; n < 4; ++n) {
                float y = (acc[m][n][q] - mu) * rs * gv[n] + bev[n];
                y = fmaxf(y, 0.f);
                if constexpr (STORE_OUT)
                    out[rb2 + fg * 64 + n * 16 + (l & 15)] = f2bf(y);
                if constexpr (FUSE_DUR) part = fmaf(y, wlv[n], part);
            }
            if constexpr (FUSE_DUR) {
#pragma unroll
                for (int o = 1; o < 16; o <<= 1) part += __shfl_xor(part, o);
                if ((l & 15) == 0) redD[row][fg] = part;
            }
        }

    if constexpr (FUSE_DUR) {
        __syncthreads();
        if (threadIdx.x < MT) {
            float s = redD[threadIdx.x][0] + redD[threadIdx.x][1]
                    + redD[threadIdx.x][2] + redD[threadIdx.x][3] + blv;
            dur[(size_t)b * T_ + t0 + threadIdx.x] = fmaxf(s, 0.f);
        }
    }
}

extern "C" void kernel_launch(void* const* d_in, const int* in_sizes, int n_in,
                              void* d_out, int out_size, void* d_ws, size_t ws_size,
                              hipStream_t stream)
{
    const float* x      = (const float*)d_in[0];
    const int*   target = (const int*)d_in[1];
    const float* w1  = (const float*)d_in[3];
    const float* b1  = (const float*)d_in[4];
    const float* g1  = (const float*)d_in[5];
    const float* be1 = (const float*)d_in[6];
    const float* w2  = (const float*)d_in[7];
    const float* b2  = (const float*)d_in[8];
    const float* g2  = (const float*)d_in[9];
    const float* be2 = (const float*)d_in[10];
    const float* wl  = (const float*)d_in[11];
    const float* bl  = (const float*)d_in[12];

    float* out = (float*)d_out;                        // (B, MEL, D)
    float* dur = out + (size_t)B_ * MEL * D_;          // (B, T)

    char* ws = (char*)d_ws;
    unsigned short* w1T = (unsigned short*)ws;         ws += (size_t)F_ * (3 * D_) * 2;
    unsigned short* w2T = (unsigned short*)ws;         ws += (size_t)F_ * (3 * F_) * 2;
    unsigned short* h1  = (unsigned short*)ws;         ws += (size_t)B_ * T_ * F_ * 2;
    int*            gidx = (int*)ws;                   // B_*MEL ints

    prep_kernel<<<PREP_WBLOCKS + B_, 256, 0, stream>>>(w1, w2, target, w1T, w2T, gidx);

    // Batch-local gather: each 64-row mel chunk owned by (b,seg,wv); conv1 takes
    // rows [0,44) of the chunk (GP=22), conv2 rows [44,64) (GP=10).
    conv_mfma_kernel<D_, float, false, true, 22, 0><<<B_ * (T_ / 64), 512, 0, stream>>>(
        x, w1T, b1, g1, be1, h1, nullptr, nullptr, nullptr, x, gidx, out);
    conv_mfma_kernel<F_, unsigned short, true, false, 10, 44><<<B_ * (T_ / 64), 512, 0, stream>>>(
        h1, w2T, b2, g2, be2, nullptr, wl, bl, dur, x, gidx, out);
}

// Round 14
// 97.705 us; speedup vs baseline: 1.7223x; 1.0444x over previous
//
#include <hip/hip_runtime.h>
#include <type_traits>

#define B_   32
#define T_   512
#define D_   512
#define F_   256
#define MEL  4096
#define EPS_ 1e-5f

typedef __attribute__((ext_vector_type(8))) short bf16x8;
typedef __attribute__((ext_vector_type(4))) float f32x4;

#define GLL16(gp, lp) \
    __builtin_amdgcn_global_load_lds((const __attribute__((address_space(1))) void*)(gp), \
                                     (__attribute__((address_space(3))) void*)(lp), 16, 0, 0)
#define BARRIER() do { asm volatile("" ::: "memory"); __builtin_amdgcn_s_barrier(); \
                       asm volatile("" ::: "memory"); } while (0)
#define MEMPIN() asm volatile("" ::: "memory")

__device__ inline unsigned short f2bf(float f) {
    unsigned u = __float_as_uint(f);
    unsigned r = (u + 0x7fff + ((u >> 16) & 1)) >> 16;   // RNE
    return (unsigned short)r;
}

// ---------------------------------------------------------------------------
// prep: weight transpose/convert (blocks 0..2303) + per-batch cumsum & idx
// precompute (blocks 2304..2335). gidx[b][pos] = source row, or -1 (masked).
// ---------------------------------------------------------------------------
#define PREP_WBLOCKS 2304   // (3*D_*F_ + 3*F_*F_) / 256

__global__ __launch_bounds__(256)
void prep_kernel(const float* __restrict__ w1, const float* __restrict__ w2,
                 const int* __restrict__ tgt,
                 unsigned short* __restrict__ w1T, unsigned short* __restrict__ w2T,
                 int* __restrict__ gidx)
{
    __shared__ int lcum[T_];
    __shared__ int wsum[4];

    int bid = blockIdx.x;
    int tid = threadIdx.x;
    if (bid < PREP_WBLOCKS) {
        int idx = bid * 256 + tid;
        if (idx < 3 * D_ * F_) {
            int kk = idx / F_, f = idx % F_;
            w1T[(size_t)f * (3 * D_) + kk] = f2bf(w1[idx]);
        } else {
            int j = idx - 3 * D_ * F_;
            int kk = j / F_, f = j % F_;
            w2T[(size_t)f * (3 * F_) + kk] = f2bf(w2[j]);
        }
        return;
    }

    int b = bid - PREP_WBLOCKS;
    int t0 = tid * 2;
    int a0 = tgt[b * T_ + t0], a1 = tgt[b * T_ + t0 + 1];
    int lane = tid & 63, w = tid >> 6;
    int v = a0 + a1;
#pragma unroll
    for (int o = 1; o < 64; o <<= 1) { int u = __shfl_up(v, o); if (lane >= o) v += u; }
    if (lane == 63) wsum[w] = v;
    __syncthreads();
    int base = 0;
#pragma unroll
    for (int i = 0; i < 4; ++i) if (i < w) base += wsum[i];
    int incl = base + v;
    lcum[t0]     = incl - a1;
    lcum[t0 + 1] = incl;
    __syncthreads();

    int total = lcum[T_ - 1];
#pragma unroll
    for (int k = 0; k < MEL / 256; ++k) {
        int pos = tid + k * 256;
        int lo = 0, hi = T_;
        while (lo < hi) { int mid = (lo + hi) >> 1; if (lcum[mid] <= pos) lo = mid + 1; else hi = mid; }
        gidx[b * MEL + pos] = (pos < total) ? min(lo, T_ - 1) : -1;
    }
}

// ---------------------------------------------------------------------------
// Fused conv1d(K=3,SAME)+bias+LN+ReLU via bf16 MFMA, with the length-regulator
// gather integrated into the SAME waves' counted-vmcnt pipeline (R7 structure,
// verbatim). 512 thr (8 waves = 2rg x 4fg), MT=64 rows.
// Per phase body (after 2nd barrier): [store set_p][load set_{p+3}][gll B_{p+2}]
// vmcnt ledger (R7-verified): prologue [gidx|G0|G1|L0|L1|L2] ->
// X(0)=8, X(1)=16, steady X=12, gll-only region X=4.
// GPHASES = phases carrying gather work (2 rows/wave each); GBASE = first row.
// STORE_OUT=false (conv2) skips the dead h2 store (dur is fused in epilogue).
// ---------------------------------------------------------------------------
template<int IN_D, typename InT, bool FUSE_DUR, bool STORE_OUT, int GPHASES, int GBASE>
__global__ __launch_bounds__(512)
void conv_mfma_kernel(const InT* __restrict__ x, const unsigned short* __restrict__ wT,
                      const float* __restrict__ bias, const float* __restrict__ gamma,
                      const float* __restrict__ beta, unsigned short* __restrict__ out,
                      const float* __restrict__ wl, const float* __restrict__ bl,
                      float* __restrict__ dur,
                      const float* __restrict__ xf, const int* __restrict__ gidx,
                      float* __restrict__ gout)
{
    constexpr int MT = 64;
    constexpr int KT = 3 * IN_D;
    constexpr int PHASES = KT / 64;                  // 24 (conv1) / 12 (conv2)
    static_assert(GPHASES <= PHASES, "gather sets must fit in phase bodies");

    __shared__ __align__(16) char xs_raw[(MT + 2) * IN_D * 2];
    __shared__ __align__(16) unsigned short xsB[2 * 16384];   // 2 x 32 KB B buffers
    __shared__ float red[MT][8];
    __shared__ float redD[MT][4];

    const int blocksPerBatch = T_ / MT;              // 8
    const int b  = blockIdx.x / blocksPerBatch;
    const int t0 = (blockIdx.x % blocksPerBatch) * MT;
    const int l  = threadIdx.x & 63;
    const int wv = threadIdx.x >> 6;                 // 0..7
    const int fg = wv & 3;
    const int rg = wv >> 2;

    // ---- stage A rows t0-1 .. t0+MT into LDS as bf16, swizzled ----
    constexpr int CH = (MT + 2) * IN_D / 8;
    for (int c = threadIdx.x; c < CH; c += 512) {
        int j  = c / (IN_D / 8);
        int d8 = (c % (IN_D / 8)) * 8;
        int t  = t0 - 1 + j;
        uint4 pk = make_uint4(0u, 0u, 0u, 0u);
        if (t >= 0 && t < T_) {
            if constexpr (std::is_same_v<InT, float>) {
                const float4* src = reinterpret_cast<const float4*>(&x[((size_t)b * T_ + t) * IN_D + d8]);
                float4 a0 = src[0], a1 = src[1];
                pk.x = (unsigned)f2bf(a0.x) | ((unsigned)f2bf(a0.y) << 16);
                pk.y = (unsigned)f2bf(a0.z) | ((unsigned)f2bf(a0.w) << 16);
                pk.z = (unsigned)f2bf(a1.x) | ((unsigned)f2bf(a1.y) << 16);
                pk.w = (unsigned)f2bf(a1.z) | ((unsigned)f2bf(a1.w) << 16);
            } else {
                pk = *reinterpret_cast<const uint4*>(&x[((size_t)b * T_ + t) * IN_D + d8]);
            }
        }
        int byte = ((j * IN_D + d8) * 2) ^ ((j & 7) << 4);
        *reinterpret_cast<uint4*>(&xs_raw[byte]) = pk;
    }

    float bv[4], gv[4], bev[4], wlv[4];
#pragma unroll
    for (int n = 0; n < 4; ++n) {
        int f = fg * 64 + n * 16 + (l & 15);
        bv[n] = bias[f]; gv[n] = gamma[f]; bev[n] = beta[f];
        if constexpr (FUSE_DUR) wlv[n] = wl[f];
    }
    float blv = 0.f;
    if constexpr (FUSE_DUR) blv = bl[0];

    asm volatile("s_waitcnt vmcnt(0)" ::: "memory");   // explicit baseline drain
    __syncthreads();

    // ---- gather assignment: 2*GPHASES consecutive rows per wave ----
    constexpr int GROWS = 2 * GPHASES;
    const int rbase = GBASE + (blockIdx.x * 8 + wv) * GROWS;
    int gidxv = gidx[rbase + min(l, GROWS - 1)];       // 1 vmem op
    MEMPIN();

    // ---- B staging: [256 f][8 kg][8 k], slot XOR kg^(f&7); gll dest linear ----
    const int sbase = wv * 4;
    auto stageB = [&](int ph, int buf) {
        int p = ph < PHASES ? ph : PHASES - 1;
        unsigned short* lb = &xsB[buf * 16384];
#pragma unroll
        for (int i = 0; i < 4; ++i) {
            int s = sbase + i;
            int c = s * 64 + l;
            int f = c >> 3;
            int kg = (c & 7) ^ (f & 7);
            const unsigned short* src = wT + (size_t)f * KT + p * 64 + kg * 8;
            GLL16(src, lb + s * 512);
        }
    };
    auto loadBfrag = [&](bf16x8* dst, int buf, int kk2) {
#pragma unroll
        for (int n = 0; n < 4; ++n) {
            int f  = fg * 64 + n * 16 + (l & 15);
            int kg = kk2 * 4 + (l >> 4);
            dst[n] = *reinterpret_cast<const bf16x8*>(&xsB[buf * 16384 + f * 64 + ((kg ^ (f & 7)) * 8)]);
        }
    };
    const int k_lane = (l >> 4) * 8;
    auto loadA = [&](bf16x8* dst, int kk) {
        int kp = kk / IN_D;
        int dbase = (kk % IN_D) + k_lane;
#pragma unroll
        for (int m = 0; m < 2; ++m) {
            int j = rg * 32 + m * 16 + (l & 15) + kp;
            int byte = ((j * IN_D + dbase) * 2) ^ ((j & 7) << 4);
            dst[m] = *reinterpret_cast<const bf16x8*>(&xs_raw[byte]);
        }
    };

    // gather set load/store: 2 rows, each row = 2 dwordx4 per lane (contiguous KB halves)
    float4 ga[3][2][2];
    auto loadSet = [&](int slot, int s) {
#pragma unroll
        for (int i = 0; i < 2; ++i) {
            int li = min(2 * s + i, GROWS - 1);        // clamp for dummy tail sets
            int ix = __shfl(gidxv, li);
            int r  = rbase + li;
            const float* src = xf + ((size_t)(r >> 12) * T_ + max(ix, 0)) * D_ + l * 4;
            ga[slot][i][0] = *reinterpret_cast<const float4*>(src);
            ga[slot][i][1] = *reinterpret_cast<const float4*>(src + 256);
        }
    };
    auto storeSet = [&](int slot, int s) {
#pragma unroll
        for (int i = 0; i < 2; ++i) {
            int li = 2 * s + i;                        // s < GPHASES here
            int ix = __shfl(gidxv, li);
            int r  = rbase + li;
            float4 a = ga[slot][i][0], c = ga[slot][i][1];
            if (ix < 0) { a = make_float4(0.f,0.f,0.f,0.f); c = make_float4(0.f,0.f,0.f,0.f); }
            float* d = gout + (size_t)r * D_ + l * 4;
            *reinterpret_cast<float4*>(d)       = a;
            *reinterpret_cast<float4*>(d + 256) = c;
        }
    };

    f32x4 acc[2][4];
#pragma unroll
    for (int m = 0; m < 2; ++m)
#pragma unroll
        for (int n = 0; n < 4; ++n) acc[m][n] = (f32x4){0.f, 0.f, 0.f, 0.f};

    // ---- prologue: pinned op groups [B0][B1][s0][s1][s2] ----
    stageB(0, 0);  MEMPIN();
    stageB(1, 1);  MEMPIN();
    loadSet(0, 0); MEMPIN();
    loadSet(1, 1); MEMPIN();
    loadSet(2, 2);

    // ---- phase loop (fully unrolled; X per ledger) ----
#pragma unroll
    for (int p = 0; p < PHASES; ++p) {
        if (p == 0)                asm volatile("s_waitcnt vmcnt(8)"  ::: "memory");
        else if (p == 1)           asm volatile("s_waitcnt vmcnt(16)" ::: "memory");
        else if (p < GPHASES + 1)  asm volatile("s_waitcnt vmcnt(12)" ::: "memory");
        else                       asm volatile("s_waitcnt vmcnt(4)"  ::: "memory");
        BARRIER();
        int buf = p & 1;
#pragma unroll
        for (int kk2 = 0; kk2 < 2; ++kk2) {
            int kk = p * 64 + kk2 * 32;
            bf16x8 Bv[4], Av[2];
            loadBfrag(Bv, buf, kk2);
            loadA(Av, kk);
#pragma unroll
            for (int m = 0; m < 2; ++m)
#pragma unroll
                for (int n = 0; n < 4; ++n)
                    acc[m][n] = __builtin_amdgcn_mfma_f32_16x16x32_bf16(Av[m], Bv[n], acc[m][n], 0, 0, 0);
        }
        BARRIER();
        // body: [st set_p][ld set_{p+3}][gll B_{p+2}]  (12 ops, or 4 in tail region)
        if (p < GPHASES) {
            storeSet(p % 3, p);
            loadSet(p % 3, p + 3);
        }
        stageB(p + 2, buf);
    }

    // ---- epilogue: bias, LN stats, LN+ReLU store, optional fused dur ----
#pragma unroll
    for (int m = 0; m < 2; ++m)
#pragma unroll
        for (int q = 0; q < 4; ++q) {
            float s = 0.f, s2 = 0.f;
#pragma unroll
            for (int n = 0; n < 4; ++n) {
                float v2 = acc[m][n][q] + bv[n];
                acc[m][n][q] = v2;
                s += v2; s2 += v2 * v2;
            }
#pragma unroll
            for (int o = 1; o < 16; o <<= 1) { s += __shfl_xor(s, o); s2 += __shfl_xor(s2, o); }
            int row = rg * 32 + m * 16 + (l >> 4) * 4 + q;   // C/D: col=l&15, row=(l>>4)*4+q
            if ((l & 15) == 0) { red[row][fg * 2] = s; red[row][fg * 2 + 1] = s2; }
        }
    __syncthreads();

#pragma unroll
    for (int m = 0; m < 2; ++m)
#pragma unroll
        for (int q = 0; q < 4; ++q) {
            int row = rg * 32 + m * 16 + (l >> 4) * 4 + q;
            float s  = red[row][0] + red[row][2] + red[row][4] + red[row][6];
            float s2 = red[row][1] + red[row][3] + red[row][5] + red[row][7];
            float mu  = s * (1.f / F_);
            float var = s2 * (1.f / F_) - mu * mu;
            float rs  = rsqrtf(var + EPS_);
            size_t rb2 = ((size_t)(b * T_ + t0 + row)) * F_;
            float part = 0.f;
#pragma unroll
            for (int n = 0; n < 4; ++n) {
                float y = (acc[m][n][q] - mu) * rs * gv[n] + bev[n];
                y = fmaxf(y, 0.f);
                if constexpr (STORE_OUT)
                    out[rb2 + fg * 64 + n * 16 + (l & 15)] = f2bf(y);
                if constexpr (FUSE_DUR) part = fmaf(y, wlv[n], part);
            }
            if constexpr (FUSE_DUR) {
#pragma unroll
                for (int o = 1; o < 16; o <<= 1) part += __shfl_xor(part, o);
                if ((l & 15) == 0) redD[row][fg] = part;
            }
        }

    if constexpr (FUSE_DUR) {
        __syncthreads();
        if (threadIdx.x < MT) {
            float s = redD[threadIdx.x][0] + redD[threadIdx.x][1]
                    + redD[threadIdx.x][2] + redD[threadIdx.x][3] + blv;
            dur[(size_t)b * T_ + t0 + threadIdx.x] = fmaxf(s, 0.f);
        }
    }
}

extern "C" void kernel_launch(void* const* d_in, const int* in_sizes, int n_in,
                              void* d_out, int out_size, void* d_ws, size_t ws_size,
                              hipStream_t stream)
{
    const float* x      = (const float*)d_in[0];
    const int*   target = (const int*)d_in[1];
    const float* w1  = (const float*)d_in[3];
    const float* b1  = (const float*)d_in[4];
    const float* g1  = (const float*)d_in[5];
    const float* be1 = (const float*)d_in[6];
    const float* w2  = (const float*)d_in[7];
    const float* b2  = (const float*)d_in[8];
    const float* g2  = (const float*)d_in[9];
    const float* be2 = (const float*)d_in[10];
    const float* wl  = (const float*)d_in[11];
    const float* bl  = (const float*)d_in[12];

    float* out = (float*)d_out;                        // (B, MEL, D)
    float* dur = out + (size_t)B_ * MEL * D_;          // (B, T)

    char* ws = (char*)d_ws;
    unsigned short* w1T = (unsigned short*)ws;         ws += (size_t)F_ * (3 * D_) * 2;
    unsigned short* w2T = (unsigned short*)ws;         ws += (size_t)F_ * (3 * F_) * 2;
    unsigned short* h1  = (unsigned short*)ws;         ws += (size_t)B_ * T_ * F_ * 2;
    int*            gidx = (int*)ws;                   // B_*MEL ints

    prep_kernel<<<PREP_WBLOCKS + B_, 256, 0, stream>>>(w1, w2, target, w1T, w2T, gidx);

    // Gather rebalance: conv1 21 sets (42 rows/wave) -> rows [0, 86016);
    // conv2 11 sets (22 rows/wave) -> rows [86016, 131072). h2 never stored.
    conv_mfma_kernel<D_, float, false, true, 21, 0><<<B_ * (T_ / 64), 512, 0, stream>>>(
        x, w1T, b1, g1, be1, h1, nullptr, nullptr, nullptr, x, gidx, out);
    conv_mfma_kernel<F_, unsigned short, true, false, 11, 86016><<<B_ * (T_ / 64), 512, 0, stream>>>(
        h1, w2T, b2, g2, be2, nullptr, wl, bl, dur, x, gidx, out);
}